// Round 5
// baseline (80.376 us; speedup 1.0000x reference)
//
#include <hip/hip_runtime.h>

// MTRNN single step, fully fused. Live computation (reference returns only y):
//   io_new = tanh([x|io|cf] @ (0.5*[Wi2io | Wio2io+I | Wcf2io])^T + 0.5*bsum)
//   y      = tanh(io_new @ Wio2o^T + bio2o)
// One block = 32 batch rows x ALL 512 io cols -> gemm2 is block-local (io_new
// handed off through 32KB LDS, no HBM round-trip, no inter-kernel sync).
// gemm1 main loop is barrier-free: fragments loaded straight from global.

typedef float f32x4 __attribute__((ext_vector_type(4)));
typedef __bf16 bf16x4 __attribute__((ext_vector_type(4)));
typedef __bf16 bf16x8 __attribute__((ext_vector_type(8)));
typedef unsigned short u16x8 __attribute__((ext_vector_type(8)));
typedef unsigned short u16x4 __attribute__((ext_vector_type(4)));

__device__ __forceinline__ unsigned short f2bf(float f) {
    unsigned u = __builtin_bit_cast(unsigned, f);
    u += 0x7FFFu + ((u >> 16) & 1u);
    return (unsigned short)(u >> 16);
}

// tanh(x) = 1 - 2/(exp(2x)+1); exp->inf gives 1, exp->0 gives -1. ~1e-6 abs.
__device__ __forceinline__ float tanh_fast(float x) {
    float e = __expf(2.0f * x);
    return 1.0f - 2.0f * __builtin_amdgcn_rcpf(e + 1.0f);
}

// ---------------------------------------------------------------------------
// Kernel 0: pack live weights to bf16.
//   wcat[512][1152] = 0.5*[Wi2io | Wio2io + I | Wcf2io]   (leaky-int folded)
//   w2  [128][512]  = Wio2o
// ---------------------------------------------------------------------------
__global__ __launch_bounds__(256) void k_convert(
    const float* __restrict__ Wi2io, const float* __restrict__ Wio2io,
    const float* __restrict__ Wcf2io, const float* __restrict__ Wio2o,
    unsigned short* __restrict__ wcat, unsigned short* __restrict__ w2)
{
    int idx = blockIdx.x * 256 + threadIdx.x;
    if (idx < 147456) {              // 512*1152/4 quads
        int n = idx / 288;
        int k = (idx - n * 288) * 4;
        const float* s;
        if (k < 128)      s = Wi2io  + n * 128 + k;
        else if (k < 640) s = Wio2io + n * 512 + (k - 128);
        else              s = Wcf2io + n * 512 + (k - 640);
        f32x4 v = *(const f32x4*)s;
        u16x4 h;
        #pragma unroll
        for (int t = 0; t < 4; ++t) {
            float f = 0.5f * v[t];
            int kk = k + t;
            if (kk >= 128 && kk < 640 && (kk - 128) == n) f += 0.5f;  // +0.5*I
            h[t] = f2bf(f);
        }
        *(u16x4*)(wcat + n * 1152 + k) = h;
    } else if (idx < 163840) {       // + 128*512/4 quads
        int q = idx - 147456;
        int n = q >> 7;
        int k = (q & 127) * 4;
        f32x4 v = *(const f32x4*)(Wio2o + n * 512 + k);
        u16x4 h; h[0]=f2bf(v[0]); h[1]=f2bf(v[1]); h[2]=f2bf(v[2]); h[3]=f2bf(v[3]);
        *(u16x4*)(w2 + n * 512 + k) = h;
    }
}

// ---------------------------------------------------------------------------
// Fused kernel. Grid 256 x 512 thr (8 waves). Block = rows [32b, 32b+32).
// gemm1: wave w owns cols [64w, 64w+64); acc[2][4] (m-frags x n-frags).
// No LDS, no barriers: A (f32->bf16) and B (bf16) fragments direct from
// global, 1-deep prefetch in named register sets.
// Handoff: tanh -> bf16 -> hlds[32][512] (XOR-swizzled), one sync.
// gemm2: swapped operands (A=w2 rows, B=io_new rows) -> D = out^T frags ->
// coalesced f32x4 stores. Wave w owns out cols [16w, 16w+16).
// ---------------------------------------------------------------------------
__global__ __launch_bounds__(512, 2) void k_fused(
    const float* __restrict__ x, const float* __restrict__ io,
    const float* __restrict__ cf,
    const unsigned short* __restrict__ wcat,
    const unsigned short* __restrict__ w2,
    const float* __restrict__ b1, const float* __restrict__ b2,
    const float* __restrict__ b3, const float* __restrict__ b4,
    float* __restrict__ out)
{
    __shared__ __align__(16) char hlds[32 * 1024];   // io_new 32x512 bf16

    const int tid  = threadIdx.x;
    const int m0   = blockIdx.x << 5;
    const int lane = tid & 63;
    const int wid  = tid >> 6;          // 0..7
    const int nw   = wid << 6;          // gemm1: 64-col group
    const int li   = lane & 15;
    const int lk   = (lane >> 4) << 3;  // k element offset: 0/8/16/24

    // gemm1 B per-lane offsets (elements): row (nw+nj*16+li), col lk
    int wboff[4];
    #pragma unroll
    for (int nj = 0; nj < 4; ++nj)
        wboff[nj] = (nw + nj * 16 + li) * 1152 + lk;

    f32x4 Ac[8], An[8];     // [mi*4 + ks*2 + half] raw f32
    u16x8 Bc[8], Bn[8];     // [nj*2 + ks]
    f32x4 acc[2][4];
    f32x4 z = {0.f, 0.f, 0.f, 0.f};
    #pragma unroll
    for (int i = 0; i < 2; ++i)
        #pragma unroll
        for (int j = 0; j < 4; ++j) acc[i][j] = z;

#define ISSUE(A_, B_, KT) do {                                                 \
        int K_ = (KT);                                                         \
        const float* sp; int st, c0;                                           \
        if (K_ < 2)       { sp = x;  st = 128; c0 = K_ << 6; }                 \
        else if (K_ < 10) { sp = io; st = 512; c0 = (K_ - 2) << 6; }           \
        else              { sp = cf; st = 512; c0 = (K_ - 10) << 6; }          \
        _Pragma("unroll")                                                      \
        for (int mi = 0; mi < 2; ++mi) {                                       \
            const float* rp = sp + (size_t)(m0 + mi * 16 + li) * st + c0 + lk; \
            _Pragma("unroll")                                                  \
            for (int ks = 0; ks < 2; ++ks) {                                   \
                A_[mi * 4 + ks * 2 + 0] = *(const f32x4*)(rp + ks * 32);       \
                A_[mi * 4 + ks * 2 + 1] = *(const f32x4*)(rp + ks * 32 + 4);   \
            }                                                                  \
        }                                                                      \
        _Pragma("unroll")                                                      \
        for (int nj = 0; nj < 4; ++nj)                                         \
            _Pragma("unroll")                                                  \
            for (int ks = 0; ks < 2; ++ks)                                     \
                B_[nj * 2 + ks] = *(const u16x8*)(wcat + wboff[nj]             \
                                                  + (K_ << 6) + ks * 32);      \
    } while (0)

#define COMPUTE(A_, B_) do {                                                   \
        _Pragma("unroll")                                                      \
        for (int ks = 0; ks < 2; ++ks) {                                       \
            bf16x8 af[2];                                                      \
            _Pragma("unroll")                                                  \
            for (int mi = 0; mi < 2; ++mi) {                                   \
                bf16x4 lo = __builtin_convertvector(A_[mi*4+ks*2+0], bf16x4);  \
                bf16x4 hi = __builtin_convertvector(A_[mi*4+ks*2+1], bf16x4);  \
                af[mi] = __builtin_shufflevector(lo, hi, 0,1,2,3,4,5,6,7);     \
            }                                                                  \
            _Pragma("unroll")                                                  \
            for (int mi = 0; mi < 2; ++mi)                                     \
                _Pragma("unroll")                                              \
                for (int nj = 0; nj < 4; ++nj)                                 \
                    acc[mi][nj] = __builtin_amdgcn_mfma_f32_16x16x32_bf16(     \
                        af[mi], __builtin_bit_cast(bf16x8, B_[nj*2+ks]),       \
                        acc[mi][nj], 0, 0, 0);                                 \
        }                                                                      \
    } while (0)

    ISSUE(Ac, Bc, 0);
    ISSUE(An, Bn, 1);
    #pragma unroll 1
    for (int i = 0; i < 9; ++i) {
        int kt = 2 * i;
        COMPUTE(Ac, Bc);
        if (kt + 2 < 18) ISSUE(Ac, Bc, kt + 2);
        COMPUTE(An, Bn);
        if (kt + 3 < 18) ISSUE(An, Bn, kt + 3);
    }
#undef ISSUE
#undef COMPUTE

    // ---- handoff: io_new = tanh(acc + 0.5*bsum) -> bf16 -> swizzled LDS ----
    #pragma unroll
    for (int nj = 0; nj < 4; ++nj) {
        int n = nw + nj * 16 + li;
        float bb = 0.5f * (b1[n] + b2[n] + b3[n]);
        #pragma unroll
        for (int mi = 0; mi < 2; ++mi) {
            #pragma unroll
            for (int r = 0; r < 4; ++r) {
                int m = mi * 16 + ((lane >> 4) << 2) + r;
                float v = tanh_fast(acc[mi][nj][r] + bb);
                int ad = ((m << 10) + (n << 1)) ^ ((m & 7) << 4);
                *(unsigned short*)(hlds + ad) = f2bf(v);
            }
        }
    }
    __syncthreads();

    // ---- gemm2: out^T frags via swapped operands ----
    const int nb = wid << 4;                       // 16 out cols per wave
    const int w2off = (nb + li) * 512 + lk;
    f32x4 acc2[2];
    acc2[0] = z; acc2[1] = z;

    #pragma unroll 4
    for (int ks = 0; ks < 16; ++ks) {
        u16x8 aw = *(const u16x8*)(w2 + w2off + ks * 32);
        #pragma unroll
        for (int mf = 0; mf < 2; ++mf) {
            int m = mf * 16 + li;
            int ad = ((m << 10) + ((ks * 32 + lk) << 1)) ^ ((m & 7) << 4);
            bf16x8 bw = *(const bf16x8*)(hlds + ad);
            acc2[mf] = __builtin_amdgcn_mfma_f32_16x16x32_bf16(
                __builtin_bit_cast(bf16x8, aw), bw, acc2[mf], 0, 0, 0);
        }
    }

    const int gnc = nb + ((lane >> 4) << 2);
    f32x4 bb4 = *(const f32x4*)(b4 + gnc);
    #pragma unroll
    for (int mf = 0; mf < 2; ++mf) {
        int gm = m0 + mf * 16 + li;
        f32x4 o;
        #pragma unroll
        for (int r = 0; r < 4; ++r)
            o[r] = tanh_fast(acc2[mf][r] + bb4[r]);
        *(f32x4*)(out + (size_t)gm * 128 + gnc) = o;
    }
}

// ---------------------------------------------------------------------------
extern "C" void kernel_launch(void* const* d_in, const int* in_sizes, int n_in,
                              void* d_out, int out_size, void* d_ws, size_t ws_size,
                              hipStream_t stream)
{
    const float* x      = (const float*)d_in[0];
    const float* io     = (const float*)d_in[1];
    const float* cf     = (const float*)d_in[2];
    // d_in[3] cs_state: dead (does not feed y)
    const float* Wi2io  = (const float*)d_in[4];
    const float* bi2io  = (const float*)d_in[5];
    const float* Wio2o  = (const float*)d_in[6];
    const float* bio2o  = (const float*)d_in[7];
    const float* Wio2io = (const float*)d_in[8];
    const float* bio2io = (const float*)d_in[9];
    const float* Wcf2io = (const float*)d_in[12];
    const float* bcf2io = (const float*)d_in[13];
    float* out = (float*)d_out;

    // workspace: wcat 1,179,648 B | w2 131,072 B
    char* ws = (char*)d_ws;
    unsigned short* wcat = (unsigned short*)ws;
    unsigned short* w2   = (unsigned short*)(ws + 1179648);

    hipLaunchKernelGGL(k_convert, dim3(640), dim3(256), 0, stream,
                       Wi2io, Wio2io, Wcf2io, Wio2o, wcat, w2);
    hipLaunchKernelGGL(k_fused, dim3(256), dim3(512), 0, stream,
                       x, io, cf, wcat, w2, bi2io, bio2io, bcf2io, bio2o, out);
}

// Round 6
// 34.616 us; speedup vs baseline: 2.3219x; 2.3219x over previous
//
#include <hip/hip_runtime.h>

// MTRNN single step. Live computation after DCE (reference returns only y):
//   io_new = tanh([x|io|cf] @ (0.5*[Wi2io | Wio2io+I | Wcf2io])^T + bsum)
//   y      = tanh(io_new @ Wio2o^T + bio2o)
// cf_new / cs_new dead. bf16 MFMA, f32 accumulate.
// Staging = global_load_lds(16B) into LINEAR LDS; bank conflicts killed by a
// chunk-XOR swizzle baked into the GLOBAL layout/offsets (rule #21), with the
// matching XOR applied on ds_read. 2-phase counted pipeline (T3-minimum):
//   STAGE(t+1,buf^1); COMPUTE(buf); s_waitcnt vmcnt(0); s_barrier.

typedef float f32x4 __attribute__((ext_vector_type(4)));
typedef __bf16 bf16x4 __attribute__((ext_vector_type(4)));
typedef __bf16 bf16x8 __attribute__((ext_vector_type(8)));
typedef unsigned short u16x4 __attribute__((ext_vector_type(4)));

__device__ __forceinline__ unsigned short f2bf(float f) {
    unsigned u = __builtin_bit_cast(unsigned, f);
    u += 0x7FFFu + ((u >> 16) & 1u);
    return (unsigned short)(u >> 16);
}

__device__ __forceinline__ float tanh_fast(float x) {
    float e = __expf(2.0f * x);
    return 1.0f - 2.0f * __builtin_amdgcn_rcpf(e + 1.0f);
}

// async global->LDS, 16B per lane. LDS dest must be wave-uniform base.
__device__ __forceinline__ void gload16(const void* g, void* l) {
    __builtin_amdgcn_global_load_lds(
        (const __attribute__((address_space(1))) void*)g,
        (__attribute__((address_space(3))) void*)l, 16, 0, 0);
}

// end-of-tile: wait in-flight stage, then barrier (one drain per tile).
__device__ __forceinline__ void wait_barrier() {
    asm volatile("s_waitcnt vmcnt(0)\n\ts_barrier" ::: "memory");
}

// ---------------------------------------------------------------------------
// Kernel 0: pack weights to bf16, CHUNK-SWIZZLED within each 64-col K-tile:
// element (n,k) -> n*L + (k&~63) + ((((k>>3)&7) ^ (n&7))<<3) + (k&7).
//   wcat[512][1152] = 0.5*[Wi2io | Wio2io + I | Wcf2io]
//   w2s [128][512]  = Wio2o
//   bsum[512]       = 0.5*(bi2io + bio2io + bcf2io)
// ---------------------------------------------------------------------------
__global__ __launch_bounds__(256) void k_convert(
    const float* __restrict__ Wi2io, const float* __restrict__ Wio2io,
    const float* __restrict__ Wcf2io, const float* __restrict__ Wio2o,
    const float* __restrict__ b1, const float* __restrict__ b2,
    const float* __restrict__ b3,
    unsigned short* __restrict__ wcat, unsigned short* __restrict__ w2s,
    float* __restrict__ bsum)
{
    int idx = blockIdx.x * 256 + threadIdx.x;
    if (idx < 147456) {              // 512*1152/4 quads
        int n = idx / 288;
        int k = (idx - n * 288) * 4;
        const float* s;
        if (k < 128)      s = Wi2io  + n * 128 + k;
        else if (k < 640) s = Wio2io + n * 512 + (k - 128);
        else              s = Wcf2io + n * 512 + (k - 640);
        f32x4 v = *(const f32x4*)s;
        u16x4 h;
        #pragma unroll
        for (int t = 0; t < 4; ++t) {
            float f = 0.5f * v[t];
            int kk = k + t;
            if (kk >= 128 && kk < 640 && (kk - 128) == n) f += 0.5f;  // +0.5*I
            h[t] = f2bf(f);
        }
        int ad = n * 1152 + (k & ~63) + ((((k >> 3) & 7) ^ (n & 7)) << 3) + (k & 7);
        *(u16x4*)(wcat + ad) = h;
    } else if (idx < 163840) {       // 128*512/4 quads
        int q = idx - 147456;
        int n = q >> 7;
        int k = (q & 127) * 4;
        f32x4 v = *(const f32x4*)(Wio2o + n * 512 + k);
        u16x4 h; h[0]=f2bf(v[0]); h[1]=f2bf(v[1]); h[2]=f2bf(v[2]); h[3]=f2bf(v[3]);
        int ad = n * 512 + (k & ~63) + ((((k >> 3) & 7) ^ (n & 7)) << 3) + (k & 7);
        *(u16x4*)(w2s + ad) = h;
    } else if (idx < 164352) {
        int n = idx - 163840;
        bsum[n] = 0.5f * (b1[n] + b2[n] + b3[n]);
    }
}

// ---------------------------------------------------------------------------
// Kernel 1: ionew = tanh(Acat @ wcat^T + bsum), bf16 out (stored swizzled).
// M=8192 N=512 K=1152. BM=64 BN=128 BK=64, 256 thr (4 waves 2x2, wave 32x64).
// Grid 512 = 2 blocks/CU, XCD-swizzled. LDS/buf: A f32 16KB | B bf16 16KB.
// ---------------------------------------------------------------------------
__global__ __launch_bounds__(256, 2) void k_gemm1(
    const float* __restrict__ x, const float* __restrict__ io,
    const float* __restrict__ cf,
    const unsigned short* __restrict__ wcat,
    const float* __restrict__ bsum,
    unsigned short* __restrict__ ionew)
{
    __shared__ __align__(16) char lds[2][32768];   // A @0 (16KB), B @16384

    const int tid = threadIdx.x, b = blockIdx.x;
    const int xcd = b & 7, idx = b >> 3;
    const int m0 = ((xcd << 4) | (idx & 15)) << 6;
    const int n0 = (idx >> 4) << 7;

    const int lane = tid & 63, wid = tid >> 6;
    const int li = lane & 15, lh = lane >> 4;
    const int wm = (wid >> 1) << 5;       // 0/32
    const int wn = (wid & 1) << 6;        // 0/64

    int a_off_x[4], a_off_s[4], b_off[4];
    #pragma unroll
    for (int j = 0; j < 4; ++j) {
        int r = (wid << 4) + 4 * j + (lane >> 4);      // A row 0..63
        int cs = (li ^ (r & 15)) << 2;                 // swizzled 16B chunk
        a_off_x[j] = (m0 + r) * 128 + cs;
        a_off_s[j] = (m0 + r) * 512 + cs;
        int rb = (wid << 5) + 8 * j + (lane >> 3);     // B row 0..127
        b_off[j] = (n0 + rb) * 1152 + ((lane & 7) << 3);  // linear (pre-swz)
    }
    const int adst = wid << 12;   // wave-uniform LDS base (4KB/wave/region)

    f32x4 zz = {0.f, 0.f, 0.f, 0.f};
    f32x4 acc[2][4];
    #pragma unroll
    for (int i = 0; i < 2; ++i)
        #pragma unroll
        for (int j = 0; j < 4; ++j) acc[i][j] = zz;

#define STAGE1(KT, BUF) do {                                                   \
        int K_ = (KT);                                                         \
        char* A_ = (BUF); char* B_ = (BUF) + 16384;                            \
        if (K_ < 2) {                                                          \
            const float* sp = x + (K_ << 6);                                   \
            _Pragma("unroll")                                                  \
            for (int j = 0; j < 4; ++j)                                        \
                gload16(sp + a_off_x[j], A_ + adst + j * 1024);                \
        } else if (K_ < 10) {                                                  \
            const float* sp = io + ((K_ - 2) << 6);                            \
            _Pragma("unroll")                                                  \
            for (int j = 0; j < 4; ++j)                                        \
                gload16(sp + a_off_s[j], A_ + adst + j * 1024);                \
        } else {                                                               \
            const float* sp = cf + ((K_ - 10) << 6);                           \
            _Pragma("unroll")                                                  \
            for (int j = 0; j < 4; ++j)                                        \
                gload16(sp + a_off_s[j], A_ + adst + j * 1024);                \
        }                                                                      \
        const unsigned short* wp = wcat + (K_ << 6);                           \
        _Pragma("unroll")                                                      \
        for (int j = 0; j < 4; ++j)                                            \
            gload16(wp + b_off[j], B_ + adst + j * 1024);                      \
    } while (0)

#define COMPUTE1(BUF) do {                                                     \
        const char* A_ = (BUF); const char* B_ = (BUF) + 16384;                \
        _Pragma("unroll")                                                      \
        for (int ks = 0; ks < 2; ++ks) {                                       \
            bf16x8 af[2];                                                      \
            _Pragma("unroll")                                                  \
            for (int mi = 0; mi < 2; ++mi) {                                   \
                int r = wm + mi * 16 + li;                                     \
                int c0 = ks * 8 + lh * 2;                                      \
                f32x4 a0 = *(const f32x4*)(A_ + r * 256 +                      \
                                           ((c0 ^ (r & 15)) << 4));            \
                f32x4 a1 = *(const f32x4*)(A_ + r * 256 +                      \
                                           (((c0 + 1) ^ (r & 15)) << 4));      \
                bf16x4 h0 = __builtin_convertvector(a0, bf16x4);               \
                bf16x4 h1 = __builtin_convertvector(a1, bf16x4);               \
                af[mi] = __builtin_shufflevector(h0, h1, 0,1,2,3,4,5,6,7);     \
            }                                                                  \
            _Pragma("unroll")                                                  \
            for (int nj = 0; nj < 4; ++nj) {                                   \
                int rb = wn + nj * 16 + li;                                    \
                int cb = ks * 4 + lh;                                          \
                bf16x8 bv = *(const bf16x8*)(B_ + rb * 128 +                   \
                                             ((cb ^ (rb & 7)) << 4));          \
                acc[0][nj] = __builtin_amdgcn_mfma_f32_16x16x32_bf16(          \
                    af[0], bv, acc[0][nj], 0, 0, 0);                           \
                acc[1][nj] = __builtin_amdgcn_mfma_f32_16x16x32_bf16(          \
                    af[1], bv, acc[1][nj], 0, 0, 0);                           \
            }                                                                  \
        }                                                                      \
    } while (0)

    STAGE1(0, lds[0]);
    wait_barrier();
    #pragma unroll 1
    for (int kt = 0; kt < 18; ++kt) {
        if (kt + 1 < 18) STAGE1(kt + 1, lds[(kt + 1) & 1]);
        COMPUTE1(lds[kt & 1]);
        wait_barrier();
    }
#undef STAGE1
#undef COMPUTE1

    // epilogue: bias+tanh, store bf16 chunk-swizzled (gemm2-ready layout)
    #pragma unroll
    for (int nj = 0; nj < 4; ++nj) {
        int gn = n0 + wn + nj * 16 + li;
        float bb = bsum[gn];
        #pragma unroll
        for (int mi = 0; mi < 2; ++mi) {
            #pragma unroll
            for (int r = 0; r < 4; ++r) {
                int gm = m0 + wm + mi * 16 + (lh << 2) + r;
                float v = tanh_fast(acc[mi][nj][r] + bb);
                int ad = gm * 512 + (gn & ~63) +
                         ((((gn >> 3) & 7) ^ (gm & 7)) << 3) + (gn & 7);
                ionew[ad] = f2bf(v);
            }
        }
    }
}

// ---------------------------------------------------------------------------
// Kernel 2: y = tanh(ionew @ w2s^T + bio2o). M=8192 N=128 K=512.
// BM=32 BN=128(full) BK=64, 256 thr (4 waves, wave 32x32). Grid 256.
// Both operands pre-swizzled bf16 -> linear gl_lds staging.
// ---------------------------------------------------------------------------
__global__ __launch_bounds__(256, 2) void k_gemm2(
    const unsigned short* __restrict__ ionew,
    const unsigned short* __restrict__ w2s,
    const float* __restrict__ b4,
    float* __restrict__ out)
{
    __shared__ __align__(16) char lds[2][20480];   // A @0 (4KB), B @4096 (16KB)

    const int tid = threadIdx.x, b = blockIdx.x;
    const int xcd = b & 7, idx = b >> 3;           // idx 0..31
    const int m0 = ((xcd << 5) | idx) << 5;        // matches gemm1 writer XCD

    const int lane = tid & 63, wid = tid >> 6;
    const int li = lane & 15, lh = lane >> 4;
    const int wn = wid << 5;                       // 32 out-cols per wave

    const int a2_off = (m0 + (wid << 3) + (lane >> 3)) * 512 + ((lane & 7) << 3);
    int b2_off[4];
    #pragma unroll
    for (int j = 0; j < 4; ++j)
        b2_off[j] = ((wid << 5) + 8 * j + (lane >> 3)) * 512 + ((lane & 7) << 3);

    f32x4 zz = {0.f, 0.f, 0.f, 0.f};
    f32x4 acc[2][2];
    acc[0][0] = zz; acc[0][1] = zz; acc[1][0] = zz; acc[1][1] = zz;

#define STAGE2(KT, BUF) do {                                                   \
        int K_ = (KT);                                                         \
        char* A_ = (BUF); char* B_ = (BUF) + 4096;                             \
        gload16(ionew + a2_off + (K_ << 6), A_ + (wid << 10));                 \
        _Pragma("unroll")                                                      \
        for (int j = 0; j < 4; ++j)                                            \
            gload16(w2s + b2_off[j] + (K_ << 6), B_ + (wid << 12) + j * 1024); \
    } while (0)

#define COMPUTE2(BUF) do {                                                     \
        const char* A_ = (BUF); const char* B_ = (BUF) + 4096;                 \
        _Pragma("unroll")                                                      \
        for (int ks = 0; ks < 2; ++ks) {                                       \
            int c = ks * 4 + lh;                                               \
            bf16x8 av[2];                                                      \
            _Pragma("unroll")                                                  \
            for (int mi = 0; mi < 2; ++mi) {                                   \
                int r = mi * 16 + li;                                          \
                av[mi] = *(const bf16x8*)(A_ + r * 128 + ((c ^ (r & 7)) << 4));\
            }                                                                  \
            _Pragma("unroll")                                                  \
            for (int nj = 0; nj < 2; ++nj) {                                   \
                int rb = wn + nj * 16 + li;                                    \
                bf16x8 bv = *(const bf16x8*)(B_ + rb * 128 +                   \
                                             ((c ^ (rb & 7)) << 4));           \
                acc[0][nj] = __builtin_amdgcn_mfma_f32_16x16x32_bf16(          \
                    av[0], bv, acc[0][nj], 0, 0, 0);                           \
                acc[1][nj] = __builtin_amdgcn_mfma_f32_16x16x32_bf16(          \
                    av[1], bv, acc[1][nj], 0, 0, 0);                           \
            }                                                                  \
        }                                                                      \
    } while (0)

    STAGE2(0, lds[0]);
    wait_barrier();
    #pragma unroll 1
    for (int kt = 0; kt < 8; ++kt) {
        if (kt + 1 < 8) STAGE2(kt + 1, lds[(kt + 1) & 1]);
        COMPUTE2(lds[kt & 1]);
        wait_barrier();
    }
#undef STAGE2
#undef COMPUTE2

    #pragma unroll
    for (int nj = 0; nj < 2; ++nj) {
        int n = wn + nj * 16 + li;
        float bb = b4[n];
        #pragma unroll
        for (int mi = 0; mi < 2; ++mi) {
            #pragma unroll
            for (int r = 0; r < 4; ++r) {
                int gm = m0 + mi * 16 + (lh << 2) + r;
                out[(size_t)gm * 128 + n] = tanh_fast(acc[mi][nj][r] + bb);
            }
        }
    }
}

// ---------------------------------------------------------------------------
extern "C" void kernel_launch(void* const* d_in, const int* in_sizes, int n_in,
                              void* d_out, int out_size, void* d_ws, size_t ws_size,
                              hipStream_t stream)
{
    const float* x      = (const float*)d_in[0];
    const float* io     = (const float*)d_in[1];
    const float* cf     = (const float*)d_in[2];
    // d_in[3] cs_state: dead (does not feed y)
    const float* Wi2io  = (const float*)d_in[4];
    const float* bi2io  = (const float*)d_in[5];
    const float* Wio2o  = (const float*)d_in[6];
    const float* bio2o  = (const float*)d_in[7];
    const float* Wio2io = (const float*)d_in[8];
    const float* bio2io = (const float*)d_in[9];
    const float* Wcf2io = (const float*)d_in[12];
    const float* bcf2io = (const float*)d_in[13];
    float* out = (float*)d_out;

    // ws: wcat 1,179,648 | w2s 131,072 | bsum 2,048 | ionew 8,388,608
    char* ws = (char*)d_ws;
    unsigned short* wcat  = (unsigned short*)ws;
    unsigned short* w2s   = (unsigned short*)(ws + 1179648);
    float*          bsum  = (float*)(ws + 1310720);
    unsigned short* ionew = (unsigned short*)(ws + 1312768);

    hipLaunchKernelGGL(k_convert, dim3(642), dim3(256), 0, stream,
                       Wi2io, Wio2io, Wcf2io, Wio2o, bi2io, bio2io, bcf2io,
                       wcat, w2s, bsum);
    hipLaunchKernelGGL(k_gemm1, dim3(512), dim3(256), 0, stream,
                       x, io, cf, wcat, bsum, ionew);
    hipLaunchKernelGGL(k_gemm2, dim3(256), dim3(256), 0, stream,
                       ionew, w2s, bio2o, out);
}